// Round 6
// baseline (4366.488 us; speedup 1.0000x reference)
//
#include <hip/hip_runtime.h>
#include <hip/hip_bf16.h>

// LSTM N=64, T=512, D=1024, H=1024 — round 6: swizzle + exchange overlap.
// r5 = 7.0us/step. Counters: SQ_LDS_BANK_CONFLICT 1.5e8 (4-way conflict on MFMA A-reads
// — 1032-stride is NOT conflict-free for the (mcol,q) pattern), rest = cross-WG h
// roundtrip, unoverlapped. This round:
//   * XOR-swizzled [16][2048B] LDS tiles: bank-group = (4kk+q)^(m&7) -> uniform (free).
//   * phase 1 = h-GEMM only, K split over all 8 waves (16-MFMA chains, 2 accs).
//   * x-GEMM moved into phase 2 with one-step lookahead (gtX double buffer), overlapped
//     with the h-wave spin/load. x-weights stream from L2 (off critical path);
//     h-weights stay in 64 VGPRs (on critical path).
//   * poll without s_sleep.
// ws: Wt 16MB | xb 64MB | hb 2x128KB | flags 512KB

#define T_T 512
#define KTOT 2048

typedef short bf16x8 __attribute__((ext_vector_type(8)));
typedef float f32x4 __attribute__((ext_vector_type(4)));
typedef unsigned u32x4 __attribute__((ext_vector_type(4)));

union B8U { u32x4 u; bf16x8 v; };
union P4 { __hip_bfloat16 h[4]; uint2 u; };

__device__ __forceinline__ float fsig(float x) {
  float e = __builtin_amdgcn_exp2f(-1.442695041f * x);
  return __builtin_amdgcn_rcpf(1.f + e);
}
__device__ __forceinline__ float ftanh(float x) {
  float e = __builtin_amdgcn_exp2f(2.885390082f * fabsf(x));
  float r = 1.f - 2.f * __builtin_amdgcn_rcpf(e + 1.f);
  return copysignf(r, x);
}

// swizzled byte offset within a [16 rows][2048 B] LDS tile (16B-granular accesses)
__device__ __forceinline__ int swz(int r, int cb) {
  return (r << 11) + (cb ^ ((r & 7) << 4));
}

// ---- Wt[a_col][k] = bf16([Wx;Wh][k][a_col]), 4096 x 2048 (proven) ----
__global__ __launch_bounds__(256) void prep_weights(const float* __restrict__ Wx,
                                                    const float* __restrict__ Wh,
                                                    __hip_bfloat16* __restrict__ Wt) {
  __shared__ float tile[64][65];
  int kb = blockIdx.x & 31;
  int cb = blockIdx.x >> 5;
  int k0 = kb << 6, c0 = cb << 6;
  const float* W = (k0 < 1024) ? Wx : Wh;
  int kr0 = k0 & 1023;
  int tid = threadIdx.x;
  int f4 = tid & 15;
  int i0 = tid >> 4;
  for (int p = 0; p < 4; ++p) {
    int i = i0 + (p << 4);
    float4 v = *(const float4*)(W + (size_t)(kr0 + i) * 4096 + c0 + (f4 << 2));
    tile[(f4 << 2) + 0][i] = v.x;
    tile[(f4 << 2) + 1][i] = v.y;
    tile[(f4 << 2) + 2][i] = v.z;
    tile[(f4 << 2) + 3][i] = v.w;
  }
  __syncthreads();
  for (int p = 0; p < 16; ++p) {
    int idx = (p << 8) + tid;
    int kl = idx & 63, cl = idx >> 6;
    Wt[(size_t)(c0 + cl) * KTOT + k0 + kl] = __float2bfloat16(tile[cl][kl]);
  }
}

// ---- x (64,512,1024) f32 -> xb (512,64,1024) bf16 ----
__global__ __launch_bounds__(256) void prep_xb(const float* __restrict__ x,
                                               __hip_bfloat16* __restrict__ xb) {
  int b = blockIdx.x;            // 32768 = 512*64
  int n = b & 63, t = b >> 6;
  const float4* src = (const float4*)(x + ((size_t)n * T_T + t) * 1024);
  __hip_bfloat16* dst = xb + ((size_t)t * 64 + n) * 1024;
  float4 v = src[threadIdx.x];
  P4 pk;
  pk.h[0] = __float2bfloat16(v.x);
  pk.h[1] = __float2bfloat16(v.y);
  pk.h[2] = __float2bfloat16(v.z);
  pk.h[3] = __float2bfloat16(v.w);
  *(uint2*)(dst + (threadIdx.x << 2)) = pk.u;
}

// ---- h0 -> bf16 into hb[0] ----
__global__ __launch_bounds__(256) void prep_state(const float* __restrict__ h0,
                                                  __hip_bfloat16* __restrict__ hb) {
  int i = blockIdx.x * 256 + threadIdx.x;   // 65536
  hb[i] = __float2bfloat16(h0[i]);
}

// ---- persistent LSTM ----
__global__ __launch_bounds__(512, 2) void lstm_persist(
    const __hip_bfloat16* __restrict__ xb,   // (512,64,1024)
    const float* __restrict__ bias,
    const __hip_bfloat16* __restrict__ Wt,   // (4096,2048)
    __hip_bfloat16* hb,                      // [2][64*1024]
    float* __restrict__ out,                 // (64,512,1024)
    unsigned* flags)                         // [512][4][64]
{
  __shared__ __align__(16) unsigned char AX[2][32768];  // x tiles (swizzled), dbuf
  __shared__ __align__(16) unsigned char AH[32768];     // h tile (swizzled)
  __shared__ float gtH[2][4][16][20];                   // [khalf][gate]
  __shared__ float gtX[2][4][16][20];                   // [t-parity][gate]
  __shared__ __align__(16) __hip_bfloat16 hrow[16][16];
  __shared__ unsigned xcnt;

  const int tid  = threadIdx.x;
  const int cgrp = blockIdx.x & 63;   // h-cols [16*cgrp,+16)
  const int bg   = blockIdx.x >> 6;   // batch rows [16*bg,+16)
  const int rows0 = bg << 4;
  const int lane = tid & 63;
  const int wv   = tid >> 6;          // 0..7
  const int gate = wv & 3;
  const int kh   = wv >> 2;           // K-half of h-part for phase 1
  const int half = wv >> 2;           // 0 = x-duty waves, 1 = h-duty waves
  const int mcol = lane & 15;
  const int q    = lane >> 4;
  const int tid2 = tid & 255;

  if (tid == 0) xcnt = 0;

  // ---- h-part weight fragments -> registers (16 x u32x4 = 64 VGPR) ----
  u32x4 wfragH[16];
  {
    const __hip_bfloat16* wp = Wt
      + ((size_t)(gate << 10) + (cgrp << 4) + mcol) * (size_t)KTOT
      + 1024 + (kh << 9) + (q << 3);
    #pragma unroll
    for (int kk = 0; kk < 16; ++kk)
      wfragH[kk] = *(const u32x4*)(wp + (kk << 5));
  }
  // x-part weights stream from L2 (off the critical path)
  const __hip_bfloat16* wpx = Wt
    + ((size_t)(wv << 10) + (cgrp << 4) + mcol) * (size_t)KTOT + (q << 3);

  // epilogue identity (x-waves = tid < 256)
  const int er = tid2 >> 4, ej = tid2 & 15;
  const int hcol = (cgrp << 4) + ej;
  const int rg = rows0 + er;
  float b_i = 0.f, b_f = 0.f, b_o = 0.f, b_g = 0.f;
  if (half == 0) {
    b_i = bias[hcol]; b_f = bias[1024 + hcol];
    b_o = bias[2048 + hcol]; b_g = bias[3072 + hcol];
  }
  float creg = 0.f;
  int poison = 0;

  // ---- prologue ----
  if (half == 0) {   // stage xb_0 -> AX[0]
    const u32x4* src = (const u32x4*)(xb + (size_t)rows0 * 1024);
    #pragma unroll
    for (int p = 0; p < 8; ++p) {
      int r = (p << 1) + (tid2 >> 7), c8 = tid2 & 127;
      u32x4 v = src[r * 128 + c8];
      *(u32x4*)(&AX[0][0] + swz(r, c8 << 4)) = v;
    }
  } else {           // stage h0 -> AH
    const u32x4* src = (const u32x4*)(hb + (size_t)rows0 * 1024);
    #pragma unroll
    for (int p = 0; p < 8; ++p) {
      int r = (p << 1) + (tid2 >> 7), c8 = tid2 & 127;
      u32x4 v = src[r * 128 + c8];
      *(u32x4*)(&AH[0] + swz(r, c8 << 4)) = v;
    }
  }
  __syncthreads();
  if (half == 0) {
    // GEMM_x(0) -> gtX[0]
    f32x4 a0 = {0,0,0,0}, a1 = {0,0,0,0};
    #pragma unroll 8
    for (int kk = 0; kk < 32; ++kk) {
      B8U a, b;
      a.u = *(const u32x4*)(&AX[0][0] + swz(mcol, (kk << 6) + (q << 4)));
      b.u = *(const u32x4*)(wpx + (kk << 5));
      if (kk & 1) a1 = __builtin_amdgcn_mfma_f32_16x16x32_bf16(a.v, b.v, a1, 0, 0, 0);
      else        a0 = __builtin_amdgcn_mfma_f32_16x16x32_bf16(a.v, b.v, a0, 0, 0, 0);
    }
    #pragma unroll
    for (int i = 0; i < 4; ++i)
      gtX[0][gate][(q << 2) + i][mcol] = a0[i] + a1[i];
    // stage xb_1 -> AX[1]
    const u32x4* src = (const u32x4*)(xb + ((size_t)64 + rows0) * 1024);
    #pragma unroll
    for (int p = 0; p < 8; ++p) {
      int r = (p << 1) + (tid2 >> 7), c8 = tid2 & 127;
      u32x4 v = src[r * 128 + c8];
      *(u32x4*)(&AX[1][0] + swz(r, c8 << 4)) = v;
    }
  }
  __syncthreads();

  for (int t = 0; t < T_T; ++t) {
    // ---- phase 1: h-GEMM only, K=512 per wave (all 8 waves) ----
    {
      f32x4 a0 = {0,0,0,0}, a1 = {0,0,0,0};
      const int kbase = kh << 10;   // byte offset of this K-half in the 2048B row
      #pragma unroll
      for (int kk = 0; kk < 16; ++kk) {
        B8U a, b;
        a.u = *(const u32x4*)(&AH[0] + swz(mcol, kbase + (kk << 6) + (q << 4)));
        b.u = wfragH[kk];
        if (kk & 1) a1 = __builtin_amdgcn_mfma_f32_16x16x32_bf16(a.v, b.v, a1, 0, 0, 0);
        else        a0 = __builtin_amdgcn_mfma_f32_16x16x32_bf16(a.v, b.v, a0, 0, 0, 0);
      }
      #pragma unroll
      for (int i = 0; i < 4; ++i)
        gtH[kh][gate][(q << 2) + i][mcol] = a0[i] + a1[i];
    }
    __syncthreads();   // barrier B: gtH ready (gtX[t&1] ready from last phase 2)
    // ---- phase 2 ----
    if (half == 0) {
      // epilogue (256 threads = 16x16 tile)
      float av_i = gtX[t & 1][0][er][ej] + gtH[0][0][er][ej] + gtH[1][0][er][ej] + b_i;
      float av_f = gtX[t & 1][1][er][ej] + gtH[0][1][er][ej] + gtH[1][1][er][ej] + b_f;
      float av_o = gtX[t & 1][2][er][ej] + gtH[0][2][er][ej] + gtH[1][2][er][ej] + b_o;
      float av_g = gtX[t & 1][3][er][ej] + gtH[0][3][er][ej] + gtH[1][3][er][ej] + b_g;
      float iv = fsig(av_i), fv = fsig(av_f), ov = fsig(av_o);
      float gv = ftanh(av_g);
      float cn = fv * creg + iv * gv;
      creg = cn;
      float hv = ov * ftanh(cn);
      hrow[er][ej] = __float2bfloat16(hv);
      if (lane == 0)
        __hip_atomic_fetch_add(&xcnt, 1u, __ATOMIC_RELAXED, __HIP_MEMORY_SCOPE_WORKGROUP);
      if (wv == 0 && t + 1 < T_T) {
        int spun = 0;
        while (!poison) {
          unsigned v = __hip_atomic_load(&xcnt, __ATOMIC_RELAXED,
                                         __HIP_MEMORY_SCOPE_WORKGROUP);
          if (v == 4u) break;
          if (++spun > (1 << 20)) poison = 1;
        }
        if (lane < 32) {   // 16x16 bf16 tile = 32 coalesced dwordx4 sc0sc1 stores
          u32x4 v = *(const u32x4*)&hrow[lane >> 1][(lane & 1) << 3];
          __hip_bfloat16* hd = hb + ((size_t)((t + 1) & 1) << 16)
                             + (size_t)(rows0 + (lane >> 1)) * 1024
                             + (cgrp << 4) + ((lane & 1) << 3);
          asm volatile("global_store_dwordx4 %0, %1, off sc0 sc1"
                       :: "v"(hd), "v"(v) : "memory");
        }
        asm volatile("s_waitcnt vmcnt(0)" ::: "memory");
        if (lane == 0) {
          __hip_atomic_store(&xcnt, 0u, __ATOMIC_RELAXED, __HIP_MEMORY_SCOPE_WORKGROUP);
          __hip_atomic_store(flags + ((unsigned)t << 8) + ((unsigned)bg << 6) + cgrp, 1u,
                             __ATOMIC_RELAXED, __HIP_MEMORY_SCOPE_AGENT);
        }
      } else if (wv == 0 && lane == 0) {
        __hip_atomic_store(&xcnt, 0u, __ATOMIC_RELAXED, __HIP_MEMORY_SCOPE_WORKGROUP);
      }
      out[((size_t)rg * T_T + t) * 1024 + hcol] = hv;   // off critical path
      // GEMM_x(t+1) from AX[(t+1)&1] (staged a step ago) -> gtX[(t+1)&1]
      if (t + 1 < T_T) {
        const unsigned char* L = &AX[(t + 1) & 1][0];
        f32x4 a0 = {0,0,0,0}, a1 = {0,0,0,0};
        #pragma unroll 8
        for (int kk = 0; kk < 32; ++kk) {
          B8U a, b;
          a.u = *(const u32x4*)(L + swz(mcol, (kk << 6) + (q << 4)));
          b.u = *(const u32x4*)(wpx + (kk << 5));
          if (kk & 1) a1 = __builtin_amdgcn_mfma_f32_16x16x32_bf16(a.v, b.v, a1, 0, 0, 0);
          else        a0 = __builtin_amdgcn_mfma_f32_16x16x32_bf16(a.v, b.v, a0, 0, 0, 0);
        }
        #pragma unroll
        for (int i = 0; i < 4; ++i)
          gtX[(t + 1) & 1][gate][(q << 2) + i][mcol] = a0[i] + a1[i];
      }
      // stage xb_{t+2} -> AX[t&1] (that buffer's readers finished last step)
      if (t + 2 < T_T) {
        const u32x4* src = (const u32x4*)(xb + ((size_t)(t + 2) * 64 + rows0) * 1024);
        unsigned char* D = &AX[t & 1][0];
        #pragma unroll
        for (int p = 0; p < 8; ++p) {
          int r = (p << 1) + (tid2 >> 7), c8 = tid2 & 127;
          u32x4 v = src[r * 128 + c8];
          *(u32x4*)(D + swz(r, c8 << 4)) = v;
        }
      }
    } else if (t + 1 < T_T) {
      // h-wave chunk: spin on its 16 producers, then stage its 256-col slice
      const int chunk = wv - 4;
      {
        unsigned* fp = flags + ((unsigned)t << 8) + ((unsigned)bg << 6)
                     + (chunk << 4) + (lane & 15);
        int spun = 0;
        while (!poison) {
          unsigned v = __hip_atomic_load(fp, __ATOMIC_RELAXED, __HIP_MEMORY_SCOPE_AGENT);
          if (__all(v != 0)) break;
          if (++spun > (1 << 13)) poison = 1;   // fast bail -> wrong answer, not hang
        }
      }
      {
        const __hip_bfloat16* hsrc = hb + ((size_t)((t + 1) & 1) << 16);
        const int c8 = lane & 31;
        const int r0 = lane >> 5;
        const char* base = (const char*)(hsrc + (size_t)(rows0 + r0) * 1024
                                         + (chunk << 8) + (c8 << 3));
        const char* p0 = base;          const char* p1 = base + 4096;
        const char* p2 = base + 8192;   const char* p3 = base + 12288;
        const char* p4 = base + 16384;  const char* p5 = base + 20480;
        const char* p6 = base + 24576;  const char* p7 = base + 28672;
        u32x4 d0, d1, d2, d3, d4, d5, d6, d7;
        asm volatile(
          "global_load_dwordx4 %0, %8, off sc0 sc1\n\t"
          "global_load_dwordx4 %1, %9, off sc0 sc1\n\t"
          "global_load_dwordx4 %2, %10, off sc0 sc1\n\t"
          "global_load_dwordx4 %3, %11, off sc0 sc1\n\t"
          "global_load_dwordx4 %4, %12, off sc0 sc1\n\t"
          "global_load_dwordx4 %5, %13, off sc0 sc1\n\t"
          "global_load_dwordx4 %6, %14, off sc0 sc1\n\t"
          "global_load_dwordx4 %7, %15, off sc0 sc1\n\t"
          "s_waitcnt vmcnt(0)"
          : "=&v"(d0), "=&v"(d1), "=&v"(d2), "=&v"(d3),
            "=&v"(d4), "=&v"(d5), "=&v"(d6), "=&v"(d7)
          : "v"(p0), "v"(p1), "v"(p2), "v"(p3),
            "v"(p4), "v"(p5), "v"(p6), "v"(p7)
          : "memory");
        const int cc = (chunk << 9) + (c8 << 4);   // byte col within 2048B row
        *(u32x4*)(&AH[0] + swz(r0 +  0, cc)) = d0;
        *(u32x4*)(&AH[0] + swz(r0 +  2, cc)) = d1;
        *(u32x4*)(&AH[0] + swz(r0 +  4, cc)) = d2;
        *(u32x4*)(&AH[0] + swz(r0 +  6, cc)) = d3;
        *(u32x4*)(&AH[0] + swz(r0 +  8, cc)) = d4;
        *(u32x4*)(&AH[0] + swz(r0 + 10, cc)) = d5;
        *(u32x4*)(&AH[0] + swz(r0 + 12, cc)) = d6;
        *(u32x4*)(&AH[0] + swz(r0 + 14, cc)) = d7;
      }
    }
    __syncthreads();   // barrier A
  }
}

extern "C" void kernel_launch(void* const* d_in, const int* in_sizes, int n_in,
                              void* d_out, int out_size, void* d_ws, size_t ws_size,
                              hipStream_t stream) {
  const float* x    = (const float*)d_in[0];   // (64,512,1024)
  const float* h0   = (const float*)d_in[1];   // (64,1024)
  const float* Wx   = (const float*)d_in[2];   // (1024,4096)
  const float* Wh   = (const float*)d_in[3];   // (1024,4096)
  const float* bias = (const float*)d_in[4];   // (4096)
  float* out = (float*)d_out;

  char* ws = (char*)d_ws;
  __hip_bfloat16* Wt  = (__hip_bfloat16*)ws;                                 // 16 MiB
  __hip_bfloat16* xb  = (__hip_bfloat16*)(ws + ((size_t)16 << 20));          // 64 MiB
  __hip_bfloat16* hbf = (__hip_bfloat16*)(ws + ((size_t)80 << 20));          // 256 KiB
  unsigned* flags     = (unsigned*)(ws + ((size_t)80 << 20) + (1u << 18));   // 512 KiB

  hipLaunchKernelGGL(prep_weights, dim3(2048), dim3(256), 0, stream, Wx, Wh, Wt);
  hipLaunchKernelGGL(prep_xb, dim3(32768), dim3(256), 0, stream, x, xb);
  hipLaunchKernelGGL(prep_state, dim3(256), dim3(256), 0, stream, h0, hbf);
  (void)hipMemsetAsync(flags, 0, (size_t)512 * 4 * 64 * sizeof(unsigned), stream);

  void* kargs[6];
  kargs[0] = (void*)&xb;
  kargs[1] = (void*)&bias;
  kargs[2] = (void*)&Wt;
  kargs[3] = (void*)&hbf;
  kargs[4] = (void*)&out;
  kargs[5] = (void*)&flags;
  (void)hipLaunchCooperativeKernel(lstm_persist, dim3(256), dim3(512), kargs, 0, stream);
}

// Round 7
// 4263.905 us; speedup vs baseline: 1.0241x; 1.0241x over previous
//
#include <hip/hip_runtime.h>
#include <hip/hip_bf16.h>

// LSTM N=64, T=512, D=1024, H=1024 — round 7: actually-register-resident weights.
// r6 post-mortem: VGPR_Count=112 < 128 needed for wfrag[32] -> compiler rematerialized
// the weight loads INSIDE the t-loop; every step re-read 256KB/WG from L2/L3 (invisible
// in FETCH_SIZE). Bank-conflict counter (~1.45e8 across 4 layouts) is the wave64-b128
// cascade floor, not a real conflict. This round (base = r5, 7.0us/step):
//   * wfrag pinned via asm("" : "+v") keep-alive -> true 128-VGPR residency.
//   * raw lgkmcnt-only barriers in the t-loop (no implicit vmcnt(0) drain).
//   * xb prefetch split: issue loads before barrier B, LDS-write in phase 2 (T14).
//   * per-x-wave h-stores (4 rows each) right after own epilogue; wave 0 aggregates
//     via LDS xcnt then posts ONE flag.
// ws: Wt 16MB | xb 64MB | hb 2x128KB | flags 512KB

#define T_T 512
#define KTOT 2048

typedef short bf16x8 __attribute__((ext_vector_type(8)));
typedef float f32x4 __attribute__((ext_vector_type(4)));
typedef unsigned u32x4 __attribute__((ext_vector_type(4)));

union B8U { u32x4 u; bf16x8 v; };
union P4 { __hip_bfloat16 h[4]; uint2 u; };

__device__ __forceinline__ float fsig(float x) {
  float e = __builtin_amdgcn_exp2f(-1.442695041f * x);
  return __builtin_amdgcn_rcpf(1.f + e);
}
__device__ __forceinline__ float ftanh(float x) {
  float e = __builtin_amdgcn_exp2f(2.885390082f * fabsf(x));
  float r = 1.f - 2.f * __builtin_amdgcn_rcpf(e + 1.f);
  return copysignf(r, x);
}

// raw barrier: LDS-visibility only; global (vmcnt) ops stay in flight
#define BAR_LGKM() do {                                   \
    asm volatile("s_waitcnt lgkmcnt(0)" ::: "memory");    \
    __builtin_amdgcn_s_barrier();                         \
    __builtin_amdgcn_sched_barrier(0);                    \
  } while (0)

// ---- Wt[a_col][k] = bf16([Wx;Wh][k][a_col]), 4096 x 2048 (proven) ----
__global__ __launch_bounds__(256) void prep_weights(const float* __restrict__ Wx,
                                                    const float* __restrict__ Wh,
                                                    __hip_bfloat16* __restrict__ Wt) {
  __shared__ float tile[64][65];
  int kb = blockIdx.x & 31;
  int cb = blockIdx.x >> 5;
  int k0 = kb << 6, c0 = cb << 6;
  const float* W = (k0 < 1024) ? Wx : Wh;
  int kr0 = k0 & 1023;
  int tid = threadIdx.x;
  int f4 = tid & 15;
  int i0 = tid >> 4;
  for (int p = 0; p < 4; ++p) {
    int i = i0 + (p << 4);
    float4 v = *(const float4*)(W + (size_t)(kr0 + i) * 4096 + c0 + (f4 << 2));
    tile[(f4 << 2) + 0][i] = v.x;
    tile[(f4 << 2) + 1][i] = v.y;
    tile[(f4 << 2) + 2][i] = v.z;
    tile[(f4 << 2) + 3][i] = v.w;
  }
  __syncthreads();
  for (int p = 0; p < 16; ++p) {
    int idx = (p << 8) + tid;
    int kl = idx & 63, cl = idx >> 6;
    Wt[(size_t)(c0 + cl) * KTOT + k0 + kl] = __float2bfloat16(tile[cl][kl]);
  }
}

// ---- x (64,512,1024) f32 -> xb (512,64,1024) bf16 ----
__global__ __launch_bounds__(256) void prep_xb(const float* __restrict__ x,
                                               __hip_bfloat16* __restrict__ xb) {
  int b = blockIdx.x;            // 32768 = 512*64
  int n = b & 63, t = b >> 6;
  const float4* src = (const float4*)(x + ((size_t)n * T_T + t) * 1024);
  __hip_bfloat16* dst = xb + ((size_t)t * 64 + n) * 1024;
  float4 v = src[threadIdx.x];
  P4 pk;
  pk.h[0] = __float2bfloat16(v.x);
  pk.h[1] = __float2bfloat16(v.y);
  pk.h[2] = __float2bfloat16(v.z);
  pk.h[3] = __float2bfloat16(v.w);
  *(uint2*)(dst + (threadIdx.x << 2)) = pk.u;
}

// ---- h0 -> bf16 into hb[0] ----
__global__ __launch_bounds__(256) void prep_state(const float* __restrict__ h0,
                                                  __hip_bfloat16* __restrict__ hb) {
  int i = blockIdx.x * 256 + threadIdx.x;   // 65536
  hb[i] = __float2bfloat16(h0[i]);
}

// ---- persistent LSTM ----
__global__ __launch_bounds__(512, 2) void lstm_persist(
    const __hip_bfloat16* __restrict__ xb,   // (512,64,1024)
    const float* __restrict__ bias,
    const __hip_bfloat16* __restrict__ Wt,   // (4096,2048)
    __hip_bfloat16* hb,                      // [2][64*1024]
    float* __restrict__ out,                 // (64,512,1024)
    unsigned* flags)                         // [512][4][64]
{
  __shared__ __align__(16) __hip_bfloat16 AX[2][16][1032];  // x tile, double buffer
  __shared__ __align__(16) __hip_bfloat16 AH[16][1032];     // h tile
  __shared__ float gtX[4][16][17];
  __shared__ float gtH[4][16][17];
  __shared__ __align__(16) __hip_bfloat16 hrow[16][16];
  __shared__ unsigned xcnt;

  const int tid  = threadIdx.x;
  const int cgrp = blockIdx.x & 63;   // h-cols [16*cgrp,+16)
  const int bg   = blockIdx.x >> 6;   // batch rows [16*bg,+16)
  const int rows0 = bg << 4;
  const int lane = tid & 63;
  const int wv   = tid >> 6;          // 0..7
  const int gate = wv & 3;
  const int half = wv >> 2;           // 0 = x-part (K 0..1023), 1 = h-part
  const int mcol = lane & 15;
  const int q    = lane >> 4;
  const int tid2 = tid & 255;

  if (tid == 0) xcnt = 0;

  // ---- weight fragments -> registers (32 x u32x4 = 128 VGPR), PINNED ----
  u32x4 wfrag[32];
  {
    const __hip_bfloat16* wp = Wt
      + ((size_t)(gate << 10) + (cgrp << 4) + mcol) * (size_t)KTOT
      + (half << 10) + (q << 3);
    #pragma unroll
    for (int kk = 0; kk < 32; ++kk)
      wfrag[kk] = *(const u32x4*)(wp + (kk << 5));
    // keep-alive: make values opaque so the compiler cannot rematerialize the
    // loads inside the t-loop (r4-r6 had VGPR_Count=112 < 128 -> it did).
    #pragma unroll
    for (int kk = 0; kk < 32; ++kk)
      asm volatile("" : "+v"(wfrag[kk]));
  }

  // epilogue identity (x-waves = tid < 256); wave wv owns rows [4wv, 4wv+4)
  const int er = tid2 >> 4, ej = tid2 & 15;
  const int hcol = (cgrp << 4) + ej;
  const int rg = rows0 + er;
  float b_i = 0.f, b_f = 0.f, b_o = 0.f, b_g = 0.f;
  if (half == 0) {
    b_i = bias[hcol]; b_f = bias[1024 + hcol];
    b_o = bias[2048 + hcol]; b_g = bias[3072 + hcol];
  }
  float creg = 0.f;
  int poison = 0;

  // ---- prologue: x-waves stage xb_0 -> AX[0]; h-waves stage h0 -> AH ----
  if (half == 0) {
    const u32x4* src = (const u32x4*)(xb + (size_t)rows0 * 1024);
    #pragma unroll
    for (int p = 0; p < 8; ++p) {
      int r = (p << 1) + (tid2 >> 7), c8 = tid2 & 127;
      u32x4 v = src[r * 128 + c8];
      *(u32x4*)&AX[0][r][c8 << 3] = v;
    }
  } else {
    const u32x4* src = (const u32x4*)(hb + (size_t)rows0 * 1024);
    #pragma unroll
    for (int p = 0; p < 8; ++p) {
      int r = (p << 1) + (tid2 >> 7), c8 = tid2 & 127;
      u32x4 v = src[r * 128 + c8];
      *(u32x4*)&AH[r][c8 << 3] = v;
    }
  }
  __syncthreads();

  for (int t = 0; t < T_T; ++t) {
    // ---- phase 1: both GEMMs (LDS A-tile x pinned-register weights) ----
    {
      const __hip_bfloat16* L = (half == 0) ? &AX[t & 1][0][0] : &AH[0][0];
      f32x4 acc = {0.f, 0.f, 0.f, 0.f};
      #pragma unroll
      for (int kk = 0; kk < 32; ++kk) {
        B8U a, b;
        a.u = *(const u32x4*)(L + (size_t)mcol * 1032 + (kk << 5) + (q << 3));
        b.u = wfrag[kk];
        acc = __builtin_amdgcn_mfma_f32_16x16x32_bf16(a.v, b.v, acc, 0, 0, 0);
      }
      float (*gt)[16][17] = (half == 0) ? gtX : gtH;
      #pragma unroll
      for (int i = 0; i < 4; ++i)
        gt[gate][(q << 2) + i][mcol] = acc[i];
    }
    // ---- T14: issue xb_{t+1} loads now; LDS-write happens in phase 2 ----
    u32x4 xld[8];
    if (half == 0 && t + 1 < T_T) {
      const u32x4* src = (const u32x4*)(xb + ((size_t)(t + 1) * 64 + rows0) * 1024);
      #pragma unroll
      for (int p = 0; p < 8; ++p) {
        int r = (p << 1) + (tid2 >> 7), c8 = tid2 & 127;
        xld[p] = src[r * 128 + c8];
      }
    }
    BAR_LGKM();   // barrier B: gt tiles ready; xld loads stay in flight
    // ---- phase 2 ----
    if (half == 0) {
      // epilogue (this wave covers rows [4wv, 4wv+4) x 16 cols)
      float av_i = gtX[0][er][ej] + gtH[0][er][ej] + b_i;
      float av_f = gtX[1][er][ej] + gtH[1][er][ej] + b_f;
      float av_o = gtX[2][er][ej] + gtH[2][er][ej] + b_o;
      float av_g = gtX[3][er][ej] + gtH[3][er][ej] + b_g;
      float iv = fsig(av_i), fv = fsig(av_f), ov = fsig(av_o);
      float gv = ftanh(av_g);
      float cn = fv * creg + iv * gv;
      creg = cn;
      float hv = ov * ftanh(cn);
      hrow[er][ej] = __float2bfloat16(hv);
      if (t + 1 < T_T) {
        // per-wave h-store: this wave's 4 rows = 8 dwordx4 packets (lanes 0-7)
        if (lane < 8) {
          int row = (wv << 2) + (lane >> 1);
          u32x4 v = *(const u32x4*)&hrow[row][(lane & 1) << 3];
          __hip_bfloat16* hd = hb + ((size_t)((t + 1) & 1) << 16)
                             + (size_t)(rows0 + row) * 1024
                             + (cgrp << 4) + ((lane & 1) << 3);
          asm volatile("global_store_dwordx4 %0, %1, off sc0 sc1"
                       :: "v"(hd), "v"(v) : "memory");
        }
        asm volatile("s_waitcnt vmcnt(0)" ::: "memory");   // own h stores at L3
        if (lane == 0)
          __hip_atomic_fetch_add(&xcnt, 1u, __ATOMIC_RELAXED,
                                 __HIP_MEMORY_SCOPE_WORKGROUP);
        if (wv == 0) {
          int spun = 0;
          while (!poison) {
            unsigned v = __hip_atomic_load(&xcnt, __ATOMIC_RELAXED,
                                           __HIP_MEMORY_SCOPE_WORKGROUP);
            if (v == 4u) break;
            if (++spun > (1 << 20)) poison = 1;
          }
          if (lane == 0) {
            __hip_atomic_store(&xcnt, 0u, __ATOMIC_RELAXED,
                               __HIP_MEMORY_SCOPE_WORKGROUP);
            __hip_atomic_store(flags + ((unsigned)t << 8) + ((unsigned)bg << 6) + cgrp,
                               1u, __ATOMIC_RELAXED, __HIP_MEMORY_SCOPE_AGENT);
          }
        }
      }
      out[((size_t)rg * T_T + t) * 1024 + hcol] = hv;   // off critical path
      // write the prefetched xb tile (loads drained by the vmcnt above / data dep)
      if (t + 1 < T_T) {
        #pragma unroll
        for (int p = 0; p < 8; ++p) {
          int r = (p << 1) + (tid2 >> 7), c8 = tid2 & 127;
          *(u32x4*)&AX[(t + 1) & 1][r][c8 << 3] = xld[p];
        }
      }
    } else if (t + 1 < T_T) {
      // h-wave chunk: spin on its 16 producers, then stage its 256-col slice
      const int chunk = wv - 4;
      {
        unsigned* fp = flags + ((unsigned)t << 8) + ((unsigned)bg << 6)
                     + (chunk << 4) + (lane & 15);
        int spun = 0;
        while (!poison) {
          unsigned v = __hip_atomic_load(fp, __ATOMIC_RELAXED, __HIP_MEMORY_SCOPE_AGENT);
          if (__all(v != 0)) break;
          __builtin_amdgcn_s_sleep(1);
          if (++spun > (1 << 16)) poison = 1;   // fast bail -> wrong answer, not hang
        }
      }
      {
        const __hip_bfloat16* hsrc = hb + ((size_t)((t + 1) & 1) << 16);
        const int c8 = lane & 31;
        const int r0 = lane >> 5;
        const char* base = (const char*)(hsrc + (size_t)(rows0 + r0) * 1024
                                         + (chunk << 8) + (c8 << 3));
        const char* p0 = base;          const char* p1 = base + 4096;
        const char* p2 = base + 8192;   const char* p3 = base + 12288;
        const char* p4 = base + 16384;  const char* p5 = base + 20480;
        const char* p6 = base + 24576;  const char* p7 = base + 28672;
        u32x4 d0, d1, d2, d3, d4, d5, d6, d7;
        asm volatile(
          "global_load_dwordx4 %0, %8, off sc0 sc1\n\t"
          "global_load_dwordx4 %1, %9, off sc0 sc1\n\t"
          "global_load_dwordx4 %2, %10, off sc0 sc1\n\t"
          "global_load_dwordx4 %3, %11, off sc0 sc1\n\t"
          "global_load_dwordx4 %4, %12, off sc0 sc1\n\t"
          "global_load_dwordx4 %5, %13, off sc0 sc1\n\t"
          "global_load_dwordx4 %6, %14, off sc0 sc1\n\t"
          "global_load_dwordx4 %7, %15, off sc0 sc1\n\t"
          "s_waitcnt vmcnt(0)"
          : "=&v"(d0), "=&v"(d1), "=&v"(d2), "=&v"(d3),
            "=&v"(d4), "=&v"(d5), "=&v"(d6), "=&v"(d7)
          : "v"(p0), "v"(p1), "v"(p2), "v"(p3),
            "v"(p4), "v"(p5), "v"(p6), "v"(p7)
          : "memory");
        const int cc = (chunk << 8) + (c8 << 3);
        *(u32x4*)&AH[r0 +  0][cc] = d0;
        *(u32x4*)&AH[r0 +  2][cc] = d1;
        *(u32x4*)&AH[r0 +  4][cc] = d2;
        *(u32x4*)&AH[r0 +  6][cc] = d3;
        *(u32x4*)&AH[r0 +  8][cc] = d4;
        *(u32x4*)&AH[r0 + 10][cc] = d5;
        *(u32x4*)&AH[r0 + 12][cc] = d6;
        *(u32x4*)&AH[r0 + 14][cc] = d7;
      }
    }
    BAR_LGKM();   // barrier A: AH(t), AX[(t+1)&1] staged; gt free for rewrite
  }
}

extern "C" void kernel_launch(void* const* d_in, const int* in_sizes, int n_in,
                              void* d_out, int out_size, void* d_ws, size_t ws_size,
                              hipStream_t stream) {
  const float* x    = (const float*)d_in[0];   // (64,512,1024)
  const float* h0   = (const float*)d_in[1];   // (64,1024)
  const float* Wx   = (const float*)d_in[2];   // (1024,4096)
  const float* Wh   = (const float*)d_in[3];   // (1024,4096)
  const float* bias = (const float*)d_in[4];   // (4096)
  float* out = (float*)d_out;

  char* ws = (char*)d_ws;
  __hip_bfloat16* Wt  = (__hip_bfloat16*)ws;                                 // 16 MiB
  __hip_bfloat16* xb  = (__hip_bfloat16*)(ws + ((size_t)16 << 20));          // 64 MiB
  __hip_bfloat16* hbf = (__hip_bfloat16*)(ws + ((size_t)80 << 20));          // 256 KiB
  unsigned* flags     = (unsigned*)(ws + ((size_t)80 << 20) + (1u << 18));   // 512 KiB

  hipLaunchKernelGGL(prep_weights, dim3(2048), dim3(256), 0, stream, Wx, Wh, Wt);
  hipLaunchKernelGGL(prep_xb, dim3(32768), dim3(256), 0, stream, x, xb);
  hipLaunchKernelGGL(prep_state, dim3(256), dim3(256), 0, stream, h0, hbf);
  (void)hipMemsetAsync(flags, 0, (size_t)512 * 4 * 64 * sizeof(unsigned), stream);

  void* kargs[6];
  kargs[0] = (void*)&xb;
  kargs[1] = (void*)&bias;
  kargs[2] = (void*)&Wt;
  kargs[3] = (void*)&hbf;
  kargs[4] = (void*)&out;
  kargs[5] = (void*)&flags;
  (void)hipLaunchCooperativeKernel(lstm_persist, dim3(256), dim3(512), kargs, 0, stream);
}